// Round 1
// baseline (907.845 us; speedup 1.0000x reference)
//
#include <hip/hip_runtime.h>

// DecoderLSTM R10: single-block ped-groups, L2-streamed weights.
// 256 blocks x 512 thr; each block owns 32 peds x FULL 256-unit hidden state.
// No cross-block exchange, no coherent ops, no atomics, no spin: the LSTM
// recurrence lives entirely in one block (c in VGPRs, h/x A-frags in LDS).
// All 640 KB of bf16 B-frags are re-streamed from per-XCD L2 every step into
// a 2-deep register ring (8 frags/wave/kc, double-buffered), MFMA 16x16x32.
// Per step: 10 kc x 16 MFMA/wave, cell+stats (shfl over 16 lanes), LN+rel by
// tid<32, x-embed. 4 plain __syncthreads per step.

typedef float  f32x4  __attribute__((ext_vector_type(4)));
typedef short  short8 __attribute__((ext_vector_type(8)));
typedef __bf16 bf16x8 __attribute__((ext_vector_type(8)));

#define WS_W     0                      // 640 KB bf16 B-frags
#define WS_BIAS  (640 * 1024)           // 4 KB
#define WS_SCAL  (WS_BIAS + 4096)       // 64 B

__device__ __forceinline__ unsigned short f2bf(float f) {
  unsigned int u = __float_as_uint(f);
  u += 0x7FFFu + ((u >> 16) & 1u);  // RNE
  return (unsigned short)(u >> 16);
}
__device__ __forceinline__ float sigm(float x) {
  return __builtin_amdgcn_rcpf(1.0f + __expf(-x));
}
__device__ __forceinline__ float tanh_(float x) {
  float ax = fabsf(x);
  float t = __expf(-2.0f * ax);
  float r = (1.0f - t) * __builtin_amdgcn_rcpf(1.0f + t);
  return x >= 0.0f ? r : -r;
}
__device__ __forceinline__ f32x4 mfma16(short8 a, short8 b, f32x4 c) {
  return __builtin_amdgcn_mfma_f32_16x16x32_bf16(
      __builtin_bit_cast(bf16x8, a), __builtin_bit_cast(bf16x8, b), c, 0, 0, 0);
}

// ---- Prologue 1: weights -> B-frag bf16 ------------------------------------
// flat short idx = (kc*64 + nt)*512 + l*8 + j
// element: row(N) = nt*16 + (l&15), col(K) = kc*32 + (l>>4)*8 + j
// kc 0..1 -> W_ih cols; kc 2..9 -> W_hh cols (kc-2)*32..
extern "C" __global__ void shuffle_weights(const float* __restrict__ Wih,
                                           const float* __restrict__ Whh,
                                           unsigned short* __restrict__ ws_w) {
  int t = blockIdx.x * 256 + threadIdx.x;  // 0..40959
  if (t >= 40960) return;
  int l = t & 63;
  int nt = (t >> 6) & 63;
  int kc = t >> 12;  // 0..9
  int row = nt * 16 + (l & 15);
  int cb = (l >> 4) * 8;
  unsigned short* dst = ws_w + (size_t)t * 8;
  const float* src = (kc < 2) ? (Wih + row * 64 + kc * 32 + cb)
                              : (Whh + row * 256 + (kc - 2) * 32 + cb);
#pragma unroll
  for (int j = 0; j < 8; j++) dst[j] = f2bf(src[j]);
}

// ---- Prologue 2: bias + scal ------------------------------------------------
extern "C" __global__ void prologue2(const float* __restrict__ b_ih,
                                     const float* __restrict__ b_hh,
                                     const float* __restrict__ ln2g,
                                     const float* __restrict__ ln2b,
                                     const float* __restrict__ posW,
                                     float* __restrict__ biasv,
                                     float* __restrict__ scal) {
  int t = threadIdx.x;  // 256
#pragma unroll
  for (int k2 = 0; k2 < 4; k2++) {
    int n = t * 4 + k2;
    biasv[n] = b_ih[n] + b_hh[n];
  }
  __shared__ float red[256][4];
  float g = ln2g[t], b = ln2b[t], p0 = posW[t], p1 = posW[256 + t];
  red[t][0] = b * p0;
  red[t][1] = b * p1;
  red[t][2] = g * p0;
  red[t][3] = g * p1;
  __syncthreads();
  for (int s = 128; s > 0; s >>= 1) {
    if (t < s) {
#pragma unroll
      for (int v = 0; v < 4; v++) red[t][v] += red[t + s][v];
    }
    __syncthreads();
  }
  if (t == 0) {
#pragma unroll
    for (int v = 0; v < 4; v++) scal[v] = red[0][v];
  }
}

// ---- Main persistent decoder ------------------------------------------------
extern "C" __global__ __launch_bounds__(512, 2) void decoder_main(
    const float* __restrict__ lpr, const float* __restrict__ h0,
    const float* __restrict__ c0, const float* __restrict__ embW,
    const float* __restrict__ embB, const float* __restrict__ ln1g,
    const float* __restrict__ ln1b, const float* __restrict__ posW,
    const float* __restrict__ posB, const float* __restrict__ ln2g,
    const unsigned short* __restrict__ ws_w,
    const float* __restrict__ biasv, const float* __restrict__ scal,
    float* __restrict__ out) {
  __shared__ unsigned short h_stage[16 * 512];  // 16 KB: [mt*8+kc][l*8+j]
  __shared__ unsigned short xh[4 * 512];        // 4 KB:  [mt*2+kc][l*8+j]
  __shared__ float partials[32 * 8 * 4];        // 4 KB:  [ped][w] f32x4
  __shared__ float n01[32][2];

  const int bid = blockIdx.x;
  const int tid = threadIdx.x;
  const int w = tid >> 6, l = tid & 63;
  const int q = l >> 4, li = l & 15;
  const int P0 = bid * 32;
  const int loff = l * 8;
  const int u0 = w * 32 + li;  // + j*16

  // per-thread base into B-frag stream: + kc*32768 + g*8192 + j*512 (shorts)
  const unsigned short* wsw = ws_w + w * 1024 + loff;

  const float K0 = scal[0], K1 = scal[1], SP0 = scal[2], SP1 = scal[3];
  const float pb0 = posB[0], pb1 = posB[1];
  const float g10 = ln1g[0], g11 = ln1g[1], b10 = ln1b[0], b11 = ln1b[1];

  float bias_r[4][2];
#pragma unroll
  for (int g = 0; g < 4; g++)
#pragma unroll
    for (int j = 0; j < 2; j++) bias_r[g][j] = biasv[g * 256 + u0 + j * 16];
  float Pp0[2], Pp1[2];
#pragma unroll
  for (int j = 0; j < 2; j++) {
    float gg = ln2g[u0 + j * 16];
    Pp0[j] = gg * posW[u0 + j * 16];
    Pp1[j] = gg * posW[256 + u0 + j * 16];
  }

  // ---- c0 ----
  f32x4 c_r[2][2];
#pragma unroll
  for (int mt = 0; mt < 2; mt++)
#pragma unroll
    for (int j = 0; j < 2; j++)
#pragma unroll
      for (int r = 0; r < 4; r++)
        c_r[mt][j][r] =
            c0[(size_t)(P0 + mt * 16 + q * 4 + r) * 256 + u0 + j * 16];

  // ---- h0 -> h_stage A-frags (32 peds x 256 units) ----
#pragma unroll
  for (int it = 0; it < 2; it++) {
    int f = tid + it * 512;  // 0..1023 short8-slots
    int ll = f & 63, fr = f >> 6;  // frag 0..15
    int mt = fr >> 3, kc = fr & 7;
    const float* src = h0 + (size_t)(P0 + mt * 16 + (ll & 15)) * 256 +
                       kc * 32 + (ll >> 4) * 8;
    float tf[8];
    *(float4*)&tf[0] = *(const float4*)(src);
    *(float4*)&tf[4] = *(const float4*)(src + 4);
    short8 sv;
#pragma unroll
    for (int j = 0; j < 8; j++) sv[j] = (short)f2bf(tf[j]);
    *(short8*)(h_stage + f * 8) = sv;
  }

  // ---- n01 from lpr ----
  if (tid < 32) {
    float r0 = lpr[(P0 + tid) * 2], r1 = lpr[(P0 + tid) * 2 + 1];
    float d = 0.5f * (r0 - r1);
    float rs = rsqrtf(d * d + 1e-5f);
    n01[tid][0] = d * rs * g10 + b10;
    n01[tid][1] = -d * rs * g11 + b11;
  }
  __syncthreads();

  // ---- x0 = embed(n01) -> xh (16 threads/ped, 4 k each) ----
  {
    const int pc = tid >> 4, s16 = tid & 15;
    float n0 = n01[pc][0], n1 = n01[pc][1];
    int mt = pc >> 4, row = pc & 15;
#pragma unroll
    for (int jj = 0; jj < 4; jj++) {
      int k = s16 * 4 + jj;
      float e = n0 * embW[k * 2] + n1 * embW[k * 2 + 1] + embB[k];
      e = e > 0.f ? e : 0.01f * e;
      xh[(mt * 2 + (k >> 5)) * 512 + (row + 16 * ((k & 31) >> 3)) * 8 +
         (k & 7)] = f2bf(e);
    }
  }
  __syncthreads();

  // ---- prefetch kc=0 B-frags into ring slot 0 ----
  short8 bb[2][4][2];  // [ring][gate][j]
#pragma unroll
  for (int g = 0; g < 4; g++)
#pragma unroll
    for (int j = 0; j < 2; j++)
      bb[0][g][j] = *(const short8*)(wsw + g * 8192 + j * 512);

  for (int st = 0; st < 30; st++) {
    f32x4 acc[2][4][2];
#pragma unroll
    for (int mt = 0; mt < 2; mt++)
#pragma unroll
      for (int g = 0; g < 4; g++)
#pragma unroll
        for (int j = 0; j < 2; j++)
          acc[mt][g][j] = (f32x4){bias_r[g][j], bias_r[g][j], bias_r[g][j],
                                  bias_r[g][j]};

    // ---- gate MFMAs: 10 kc, B streamed from L2 (2-deep register ring) ----
#pragma unroll
    for (int kc = 0; kc < 10; kc++) {
      const int nkc = (kc == 9) ? 0 : kc + 1;  // wrap -> next step's kc0
      const unsigned short* wp = wsw + nkc * 32768;
#pragma unroll
      for (int g = 0; g < 4; g++)
#pragma unroll
        for (int j = 0; j < 2; j++)
          bb[(kc + 1) & 1][g][j] = *(const short8*)(wp + g * 8192 + j * 512);
      short8 a0, a1;
      if (kc < 2) {
        a0 = *(const short8*)(xh + kc * 512 + loff);
        a1 = *(const short8*)(xh + (2 + kc) * 512 + loff);
      } else {
        a0 = *(const short8*)(h_stage + (kc - 2) * 512 + loff);
        a1 = *(const short8*)(h_stage + (8 + kc - 2) * 512 + loff);
      }
#pragma unroll
      for (int g = 0; g < 4; g++)
#pragma unroll
        for (int j = 0; j < 2; j++) {
          acc[0][g][j] = mfma16(a0, bb[kc & 1][g][j], acc[0][g][j]);
          acc[1][g][j] = mfma16(a1, bb[kc & 1][g][j], acc[1][g][j]);
        }
    }
    __syncthreads();  // A: all xh/h_stage reads done

    // ---- cell: c/h update, h -> h_stage A-frags, stats reduce ----
#pragma unroll
    for (int mt = 0; mt < 2; mt++) {
      float sh[4], sh2[4], sA[4], sB[4];
#pragma unroll
      for (int r = 0; r < 4; r++) {
        sh[r] = 0.f; sh2[r] = 0.f; sA[r] = 0.f; sB[r] = 0.f;
      }
#pragma unroll
      for (int j = 0; j < 2; j++) {
#pragma unroll
        for (int r = 0; r < 4; r++) {
          float iv = sigm(acc[mt][0][j][r]);
          float fv = sigm(acc[mt][1][j][r]);
          float gv = tanh_(acc[mt][2][j][r]);
          float ov = sigm(acc[mt][3][j][r]);
          float cc = fv * c_r[mt][j][r] + iv * gv;
          c_r[mt][j][r] = cc;
          float hv = ov * tanh_(cc);
          // unit u = w*32 + j*16 + li -> frag kc = w, col = j*16+li
          h_stage[(mt * 8 + w) * 512 +
                  ((q * 4 + r) + 16 * (j * 2 + (li >> 3))) * 8 + (li & 7)] =
              f2bf(hv);
          sh[r] += hv;
          sh2[r] += hv * hv;
          sA[r] += hv * Pp0[j];
          sB[r] += hv * Pp1[j];
        }
      }
#pragma unroll
      for (int mask = 1; mask <= 8; mask <<= 1) {
#pragma unroll
        for (int r = 0; r < 4; r++) {
          sh[r] += __shfl_xor(sh[r], mask, 64);
          sh2[r] += __shfl_xor(sh2[r], mask, 64);
          sA[r] += __shfl_xor(sA[r], mask, 64);
          sB[r] += __shfl_xor(sB[r], mask, 64);
        }
      }
      if (li == 0) {
#pragma unroll
        for (int r = 0; r < 4; r++)
          *(f32x4*)(partials + ((mt * 16 + q * 4 + r) * 8 + w) * 4) =
              (f32x4){sh[r], sh2[r], sA[r], sB[r]};
      }
    }
    __syncthreads();  // B: h_stage(t+1) + partials complete

    // ---- LN + rel + out + n01 (one thread per ped) ----
    if (tid < 32) {
      f32x4 sv = *(const f32x4*)(partials + tid * 32);
#pragma unroll
      for (int ww = 1; ww < 8; ww++) {
        f32x4 t2 = *(const f32x4*)(partials + (tid * 8 + ww) * 4);
        sv.x += t2.x; sv.y += t2.y; sv.z += t2.z; sv.w += t2.w;
      }
      float mu = sv.x * (1.0f / 256.0f);
      float var = sv.y * (1.0f / 256.0f) - mu * mu;
      float rsig = rsqrtf(var + 1e-5f);
      float rel0 = sigm(rsig * (sv.z - mu * SP0) + K0 + pb0);
      float rel1 = sigm(rsig * (sv.w - mu * SP1) + K1 + pb1);
      *(float2*)(out + (size_t)st * 16384 + (P0 + tid) * 2) =
          make_float2(rel0, rel1);
      float d = 0.5f * (rel0 - rel1);
      float rs = rsqrtf(d * d + 1e-5f);
      n01[tid][0] = d * rs * g10 + b10;
      n01[tid][1] = -d * rs * g11 + b11;
    }
    __syncthreads();  // C: n01 ready

    // ---- x_{t+1} = embed(rel) -> xh ----
    {
      const int pc = tid >> 4, s16 = tid & 15;
      float n0 = n01[pc][0], n1 = n01[pc][1];
      int mt = pc >> 4, row = pc & 15;
#pragma unroll
      for (int jj = 0; jj < 4; jj++) {
        int k = s16 * 4 + jj;
        float e = n0 * embW[k * 2] + n1 * embW[k * 2 + 1] + embB[k];
        e = e > 0.f ? e : 0.01f * e;
        xh[(mt * 2 + (k >> 5)) * 512 + (row + 16 * ((k & 31) >> 3)) * 8 +
           (k & 7)] = f2bf(e);
      }
    }
    __syncthreads();  // D: xh ready for next step
  }
}

extern "C" void kernel_launch(void* const* d_in, const int* in_sizes, int n_in,
                              void* d_out, int out_size, void* d_ws,
                              size_t ws_size, hipStream_t stream) {
  (void)in_sizes; (void)n_in; (void)out_size; (void)ws_size;
  const float* lpr  = (const float*)d_in[1];
  const float* h0   = (const float*)d_in[2];
  const float* c0   = (const float*)d_in[3];
  const float* Wih  = (const float*)d_in[4];
  const float* Whh  = (const float*)d_in[5];
  const float* b_ih = (const float*)d_in[6];
  const float* b_hh = (const float*)d_in[7];
  const float* embW = (const float*)d_in[8];
  const float* embB = (const float*)d_in[9];
  const float* ln1g = (const float*)d_in[10];
  const float* ln1b = (const float*)d_in[11];
  const float* posW = (const float*)d_in[12];
  const float* posB = (const float*)d_in[13];
  const float* ln2g = (const float*)d_in[14];
  const float* ln2b = (const float*)d_in[15];

  char* ws = (char*)d_ws;
  unsigned short* ws_w = (unsigned short*)(ws + WS_W);
  float* biasv  = (float*)(ws + WS_BIAS);
  float* scal   = (float*)(ws + WS_SCAL);

  shuffle_weights<<<dim3(160), dim3(256), 0, stream>>>(Wih, Whh, ws_w);
  prologue2<<<dim3(1), dim3(256), 0, stream>>>(b_ih, b_hh, ln2g, ln2b, posW,
                                               biasv, scal);
  decoder_main<<<dim3(256), dim3(512), 0, stream>>>(
      lpr, h0, c0, embW, embB, ln1g, ln1b, posW, posB, ln2g, ws_w, biasv,
      scal, (float*)d_out);
}

// Round 2
// 907.138 us; speedup vs baseline: 1.0008x; 1.0008x over previous
//
#include <hip/hip_runtime.h>

// DecoderLSTM R11: R10 structure with the spill bug fixed.
// R10 failed because __launch_bounds__(512,2) caps VGPRs at 128 while the
// kernel needs ~200 (bb ring 64 + acc 64 + c_r 16 + misc) -> ~50 regs spilled
// to scratch in the step loop (129 MB WRITE_SIZE, 1.89 GB FETCH_SIZE, L2
// thrashed). Fix: __launch_bounds__(512,1) -> 256-VGPR cap (2 waves/SIMD,
// same 8 waves/CU occupancy at grid=256 blocks = 1 block/CU).
//
// Design: 256 blocks x 512 thr; each block owns 32 peds x FULL 256-unit
// hidden state. No cross-block exchange/atomics/spin. All 640 KB bf16
// B-frags re-streamed from per-XCD L2 every step into a 2-deep register
// ring, MFMA 16x16x32. 4 plain __syncthreads per step.

typedef float  f32x4  __attribute__((ext_vector_type(4)));
typedef short  short8 __attribute__((ext_vector_type(8)));
typedef __bf16 bf16x8 __attribute__((ext_vector_type(8)));

#define WS_W     0                      // 640 KB bf16 B-frags
#define WS_BIAS  (640 * 1024)           // 4 KB
#define WS_SCAL  (WS_BIAS + 4096)       // 64 B

__device__ __forceinline__ unsigned short f2bf(float f) {
  unsigned int u = __float_as_uint(f);
  u += 0x7FFFu + ((u >> 16) & 1u);  // RNE
  return (unsigned short)(u >> 16);
}
__device__ __forceinline__ float sigm(float x) {
  return __builtin_amdgcn_rcpf(1.0f + __expf(-x));
}
__device__ __forceinline__ float tanh_(float x) {
  float ax = fabsf(x);
  float t = __expf(-2.0f * ax);
  float r = (1.0f - t) * __builtin_amdgcn_rcpf(1.0f + t);
  return x >= 0.0f ? r : -r;
}
__device__ __forceinline__ f32x4 mfma16(short8 a, short8 b, f32x4 c) {
  return __builtin_amdgcn_mfma_f32_16x16x32_bf16(
      __builtin_bit_cast(bf16x8, a), __builtin_bit_cast(bf16x8, b), c, 0, 0, 0);
}

// ---- Prologue 1: weights -> B-frag bf16 ------------------------------------
// flat short idx = (kc*64 + nt)*512 + l*8 + j
// element: row(N) = nt*16 + (l&15), col(K) = kc*32 + (l>>4)*8 + j
// kc 0..1 -> W_ih cols; kc 2..9 -> W_hh cols (kc-2)*32..
extern "C" __global__ void shuffle_weights(const float* __restrict__ Wih,
                                           const float* __restrict__ Whh,
                                           unsigned short* __restrict__ ws_w) {
  int t = blockIdx.x * 256 + threadIdx.x;  // 0..40959
  if (t >= 40960) return;
  int l = t & 63;
  int nt = (t >> 6) & 63;
  int kc = t >> 12;  // 0..9
  int row = nt * 16 + (l & 15);
  int cb = (l >> 4) * 8;
  unsigned short* dst = ws_w + (size_t)t * 8;
  const float* src = (kc < 2) ? (Wih + row * 64 + kc * 32 + cb)
                              : (Whh + row * 256 + (kc - 2) * 32 + cb);
#pragma unroll
  for (int j = 0; j < 8; j++) dst[j] = f2bf(src[j]);
}

// ---- Prologue 2: bias + scal ------------------------------------------------
extern "C" __global__ void prologue2(const float* __restrict__ b_ih,
                                     const float* __restrict__ b_hh,
                                     const float* __restrict__ ln2g,
                                     const float* __restrict__ ln2b,
                                     const float* __restrict__ posW,
                                     float* __restrict__ biasv,
                                     float* __restrict__ scal) {
  int t = threadIdx.x;  // 256
#pragma unroll
  for (int k2 = 0; k2 < 4; k2++) {
    int n = t * 4 + k2;
    biasv[n] = b_ih[n] + b_hh[n];
  }
  __shared__ float red[256][4];
  float g = ln2g[t], b = ln2b[t], p0 = posW[t], p1 = posW[256 + t];
  red[t][0] = b * p0;
  red[t][1] = b * p1;
  red[t][2] = g * p0;
  red[t][3] = g * p1;
  __syncthreads();
  for (int s = 128; s > 0; s >>= 1) {
    if (t < s) {
#pragma unroll
      for (int v = 0; v < 4; v++) red[t][v] += red[t + s][v];
    }
    __syncthreads();
  }
  if (t == 0) {
#pragma unroll
    for (int v = 0; v < 4; v++) scal[v] = red[0][v];
  }
}

// ---- Main persistent decoder ------------------------------------------------
extern "C" __global__ __launch_bounds__(512, 1) void decoder_main(
    const float* __restrict__ lpr, const float* __restrict__ h0,
    const float* __restrict__ c0, const float* __restrict__ embW,
    const float* __restrict__ embB, const float* __restrict__ ln1g,
    const float* __restrict__ ln1b, const float* __restrict__ posW,
    const float* __restrict__ posB, const float* __restrict__ ln2g,
    const unsigned short* __restrict__ ws_w,
    const float* __restrict__ biasv, const float* __restrict__ scal,
    float* __restrict__ out) {
  __shared__ unsigned short h_stage[16 * 512];  // 16 KB: [mt*8+kc][l*8+j]
  __shared__ unsigned short xh[4 * 512];        // 4 KB:  [mt*2+kc][l*8+j]
  __shared__ float partials[32 * 8 * 4];        // 4 KB:  [ped][w] f32x4
  __shared__ float n01[32][2];

  const int bid = blockIdx.x;
  const int tid = threadIdx.x;
  const int w = tid >> 6, l = tid & 63;
  const int q = l >> 4, li = l & 15;
  const int P0 = bid * 32;
  const int loff = l * 8;
  const int u0 = w * 32 + li;  // + j*16

  // per-thread base into B-frag stream: + kc*32768 + g*8192 + j*512 (shorts)
  const unsigned short* wsw = ws_w + w * 1024 + loff;

  const float K0 = scal[0], K1 = scal[1], SP0 = scal[2], SP1 = scal[3];
  const float pb0 = posB[0], pb1 = posB[1];
  const float g10 = ln1g[0], g11 = ln1g[1], b10 = ln1b[0], b11 = ln1b[1];

  float bias_r[4][2];
#pragma unroll
  for (int g = 0; g < 4; g++)
#pragma unroll
    for (int j = 0; j < 2; j++) bias_r[g][j] = biasv[g * 256 + u0 + j * 16];
  float Pp0[2], Pp1[2];
#pragma unroll
  for (int j = 0; j < 2; j++) {
    float gg = ln2g[u0 + j * 16];
    Pp0[j] = gg * posW[u0 + j * 16];
    Pp1[j] = gg * posW[256 + u0 + j * 16];
  }

  // ---- c0 ----
  f32x4 c_r[2][2];
#pragma unroll
  for (int mt = 0; mt < 2; mt++)
#pragma unroll
    for (int j = 0; j < 2; j++)
#pragma unroll
      for (int r = 0; r < 4; r++)
        c_r[mt][j][r] =
            c0[(size_t)(P0 + mt * 16 + q * 4 + r) * 256 + u0 + j * 16];

  // ---- h0 -> h_stage A-frags (32 peds x 256 units) ----
#pragma unroll
  for (int it = 0; it < 2; it++) {
    int f = tid + it * 512;  // 0..1023 short8-slots
    int ll = f & 63, fr = f >> 6;  // frag 0..15
    int mt = fr >> 3, kc = fr & 7;
    const float* src = h0 + (size_t)(P0 + mt * 16 + (ll & 15)) * 256 +
                       kc * 32 + (ll >> 4) * 8;
    float tf[8];
    *(float4*)&tf[0] = *(const float4*)(src);
    *(float4*)&tf[4] = *(const float4*)(src + 4);
    short8 sv;
#pragma unroll
    for (int j = 0; j < 8; j++) sv[j] = (short)f2bf(tf[j]);
    *(short8*)(h_stage + f * 8) = sv;
  }

  // ---- n01 from lpr ----
  if (tid < 32) {
    float r0 = lpr[(P0 + tid) * 2], r1 = lpr[(P0 + tid) * 2 + 1];
    float d = 0.5f * (r0 - r1);
    float rs = rsqrtf(d * d + 1e-5f);
    n01[tid][0] = d * rs * g10 + b10;
    n01[tid][1] = -d * rs * g11 + b11;
  }
  __syncthreads();

  // ---- x0 = embed(n01) -> xh (16 threads/ped, 4 k each) ----
  {
    const int pc = tid >> 4, s16 = tid & 15;
    float n0 = n01[pc][0], n1 = n01[pc][1];
    int mt = pc >> 4, row = pc & 15;
#pragma unroll
    for (int jj = 0; jj < 4; jj++) {
      int k = s16 * 4 + jj;
      float e = n0 * embW[k * 2] + n1 * embW[k * 2 + 1] + embB[k];
      e = e > 0.f ? e : 0.01f * e;
      xh[(mt * 2 + (k >> 5)) * 512 + (row + 16 * ((k & 31) >> 3)) * 8 +
         (k & 7)] = f2bf(e);
    }
  }
  __syncthreads();

  // ---- prefetch kc=0 B-frags into ring slot 0 ----
  short8 bb[2][4][2];  // [ring][gate][j]
#pragma unroll
  for (int g = 0; g < 4; g++)
#pragma unroll
    for (int j = 0; j < 2; j++)
      bb[0][g][j] = *(const short8*)(wsw + g * 8192 + j * 512);

  for (int st = 0; st < 30; st++) {
    f32x4 acc[2][4][2];
#pragma unroll
    for (int mt = 0; mt < 2; mt++)
#pragma unroll
      for (int g = 0; g < 4; g++)
#pragma unroll
        for (int j = 0; j < 2; j++)
          acc[mt][g][j] = (f32x4){bias_r[g][j], bias_r[g][j], bias_r[g][j],
                                  bias_r[g][j]};

    // ---- gate MFMAs: 10 kc, B streamed from L2 (2-deep register ring) ----
#pragma unroll
    for (int kc = 0; kc < 10; kc++) {
      const int nkc = (kc == 9) ? 0 : kc + 1;  // wrap -> next step's kc0
      const unsigned short* wp = wsw + nkc * 32768;
#pragma unroll
      for (int g = 0; g < 4; g++)
#pragma unroll
        for (int j = 0; j < 2; j++)
          bb[(kc + 1) & 1][g][j] = *(const short8*)(wp + g * 8192 + j * 512);
      short8 a0, a1;
      if (kc < 2) {
        a0 = *(const short8*)(xh + kc * 512 + loff);
        a1 = *(const short8*)(xh + (2 + kc) * 512 + loff);
      } else {
        a0 = *(const short8*)(h_stage + (kc - 2) * 512 + loff);
        a1 = *(const short8*)(h_stage + (8 + kc - 2) * 512 + loff);
      }
#pragma unroll
      for (int g = 0; g < 4; g++)
#pragma unroll
        for (int j = 0; j < 2; j++) {
          acc[0][g][j] = mfma16(a0, bb[kc & 1][g][j], acc[0][g][j]);
          acc[1][g][j] = mfma16(a1, bb[kc & 1][g][j], acc[1][g][j]);
        }
    }
    __syncthreads();  // A: all xh/h_stage reads done

    // ---- cell: c/h update, h -> h_stage A-frags, stats reduce ----
#pragma unroll
    for (int mt = 0; mt < 2; mt++) {
      float sh[4], sh2[4], sA[4], sB[4];
#pragma unroll
      for (int r = 0; r < 4; r++) {
        sh[r] = 0.f; sh2[r] = 0.f; sA[r] = 0.f; sB[r] = 0.f;
      }
#pragma unroll
      for (int j = 0; j < 2; j++) {
#pragma unroll
        for (int r = 0; r < 4; r++) {
          float iv = sigm(acc[mt][0][j][r]);
          float fv = sigm(acc[mt][1][j][r]);
          float gv = tanh_(acc[mt][2][j][r]);
          float ov = sigm(acc[mt][3][j][r]);
          float cc = fv * c_r[mt][j][r] + iv * gv;
          c_r[mt][j][r] = cc;
          float hv = ov * tanh_(cc);
          // unit u = w*32 + j*16 + li -> frag kc = w, col = j*16+li
          h_stage[(mt * 8 + w) * 512 +
                  ((q * 4 + r) + 16 * (j * 2 + (li >> 3))) * 8 + (li & 7)] =
              f2bf(hv);
          sh[r] += hv;
          sh2[r] += hv * hv;
          sA[r] += hv * Pp0[j];
          sB[r] += hv * Pp1[j];
        }
      }
#pragma unroll
      for (int mask = 1; mask <= 8; mask <<= 1) {
#pragma unroll
        for (int r = 0; r < 4; r++) {
          sh[r] += __shfl_xor(sh[r], mask, 64);
          sh2[r] += __shfl_xor(sh2[r], mask, 64);
          sA[r] += __shfl_xor(sA[r], mask, 64);
          sB[r] += __shfl_xor(sB[r], mask, 64);
        }
      }
      if (li == 0) {
#pragma unroll
        for (int r = 0; r < 4; r++)
          *(f32x4*)(partials + ((mt * 16 + q * 4 + r) * 8 + w) * 4) =
              (f32x4){sh[r], sh2[r], sA[r], sB[r]};
      }
    }
    __syncthreads();  // B: h_stage(t+1) + partials complete

    // ---- LN + rel + out + n01 (one thread per ped) ----
    if (tid < 32) {
      f32x4 sv = *(const f32x4*)(partials + tid * 32);
#pragma unroll
      for (int ww = 1; ww < 8; ww++) {
        f32x4 t2 = *(const f32x4*)(partials + (tid * 8 + ww) * 4);
        sv.x += t2.x; sv.y += t2.y; sv.z += t2.z; sv.w += t2.w;
      }
      float mu = sv.x * (1.0f / 256.0f);
      float var = sv.y * (1.0f / 256.0f) - mu * mu;
      float rsig = rsqrtf(var + 1e-5f);
      float rel0 = sigm(rsig * (sv.z - mu * SP0) + K0 + pb0);
      float rel1 = sigm(rsig * (sv.w - mu * SP1) + K1 + pb1);
      *(float2*)(out + (size_t)st * 16384 + (P0 + tid) * 2) =
          make_float2(rel0, rel1);
      float d = 0.5f * (rel0 - rel1);
      float rs = rsqrtf(d * d + 1e-5f);
      n01[tid][0] = d * rs * g10 + b10;
      n01[tid][1] = -d * rs * g11 + b11;
    }
    __syncthreads();  // C: n01 ready

    // ---- x_{t+1} = embed(rel) -> xh ----
    {
      const int pc = tid >> 4, s16 = tid & 15;
      float n0 = n01[pc][0], n1 = n01[pc][1];
      int mt = pc >> 4, row = pc & 15;
#pragma unroll
      for (int jj = 0; jj < 4; jj++) {
        int k = s16 * 4 + jj;
        float e = n0 * embW[k * 2] + n1 * embW[k * 2 + 1] + embB[k];
        e = e > 0.f ? e : 0.01f * e;
        xh[(mt * 2 + (k >> 5)) * 512 + (row + 16 * ((k & 31) >> 3)) * 8 +
           (k & 7)] = f2bf(e);
      }
    }
    __syncthreads();  // D: xh ready for next step
  }
}

extern "C" void kernel_launch(void* const* d_in, const int* in_sizes, int n_in,
                              void* d_out, int out_size, void* d_ws,
                              size_t ws_size, hipStream_t stream) {
  (void)in_sizes; (void)n_in; (void)out_size; (void)ws_size;
  const float* lpr  = (const float*)d_in[1];
  const float* h0   = (const float*)d_in[2];
  const float* c0   = (const float*)d_in[3];
  const float* Wih  = (const float*)d_in[4];
  const float* Whh  = (const float*)d_in[5];
  const float* b_ih = (const float*)d_in[6];
  const float* b_hh = (const float*)d_in[7];
  const float* embW = (const float*)d_in[8];
  const float* embB = (const float*)d_in[9];
  const float* ln1g = (const float*)d_in[10];
  const float* ln1b = (const float*)d_in[11];
  const float* posW = (const float*)d_in[12];
  const float* posB = (const float*)d_in[13];
  const float* ln2g = (const float*)d_in[14];
  const float* ln2b = (const float*)d_in[15];

  char* ws = (char*)d_ws;
  unsigned short* ws_w = (unsigned short*)(ws + WS_W);
  float* biasv  = (float*)(ws + WS_BIAS);
  float* scal   = (float*)(ws + WS_SCAL);

  shuffle_weights<<<dim3(160), dim3(256), 0, stream>>>(Wih, Whh, ws_w);
  prologue2<<<dim3(1), dim3(256), 0, stream>>>(b_ih, b_hh, ln2g, ln2b, posW,
                                               biasv, scal);
  decoder_main<<<dim3(256), dim3(512), 0, stream>>>(
      lpr, h0, c0, embW, embB, ln1g, ln1b, posW, posB, ln2g, ws_w, biasv,
      scal, (float*)d_out);
}

// Round 3
// 906.662 us; speedup vs baseline: 1.0013x; 1.0005x over previous
//
#include <hip/hip_runtime.h>

// DecoderLSTM R12: R11 design, scratch-proofed.
// R10/R11 evidence: launch_bounds (512,2)->(512,1) changed NOTHING (identical
// FETCH/WRITE/VGPR=128) => the spill was structural (rule #20: runtime-indexed
// ring bb[(kc±1)&1] in a partially-unrolled kc loop -> scratch), not
// pressure-driven. ~126 MB/step-loop scratch traffic thrashed per-XCD L2,
// evicting the 640 KB weight set -> 1.9 GB L3/HBM refetch.
// Fix: hand-unrolled 10-stage kc pipeline with NAMED double-buffer sets
// (bA/bB), every register-array index literal. No other design change:
// 256 blocks x 512 thr, each block owns 32 peds x full 256-unit state,
// weights re-streamed from per-XCD L2 each step, MFMA 16x16x32 bf16,
// 4 plain __syncthreads per step, no cross-block traffic.

typedef float  f32x4  __attribute__((ext_vector_type(4)));
typedef short  short8 __attribute__((ext_vector_type(8)));
typedef __bf16 bf16x8 __attribute__((ext_vector_type(8)));

#define WS_W     0                      // 640 KB bf16 B-frags
#define WS_BIAS  (640 * 1024)           // 4 KB
#define WS_SCAL  (WS_BIAS + 4096)       // 64 B

__device__ __forceinline__ unsigned short f2bf(float f) {
  unsigned int u = __float_as_uint(f);
  u += 0x7FFFu + ((u >> 16) & 1u);  // RNE
  return (unsigned short)(u >> 16);
}
__device__ __forceinline__ float sigm(float x) {
  return __builtin_amdgcn_rcpf(1.0f + __expf(-x));
}
__device__ __forceinline__ float tanh_(float x) {
  float ax = fabsf(x);
  float t = __expf(-2.0f * ax);
  float r = (1.0f - t) * __builtin_amdgcn_rcpf(1.0f + t);
  return x >= 0.0f ? r : -r;
}
__device__ __forceinline__ f32x4 mfma16(short8 a, short8 b, f32x4 c) {
  return __builtin_amdgcn_mfma_f32_16x16x32_bf16(
      __builtin_bit_cast(bf16x8, a), __builtin_bit_cast(bf16x8, b), c, 0, 0, 0);
}

// ---- Prologue 1: weights -> B-frag bf16 ------------------------------------
// flat short idx = (kc*64 + nt)*512 + l*8 + j
// element: row(N) = nt*16 + (l&15), col(K) = kc*32 + (l>>4)*8 + j
// kc 0..1 -> W_ih cols; kc 2..9 -> W_hh cols (kc-2)*32..
extern "C" __global__ void shuffle_weights(const float* __restrict__ Wih,
                                           const float* __restrict__ Whh,
                                           unsigned short* __restrict__ ws_w) {
  int t = blockIdx.x * 256 + threadIdx.x;  // 0..40959
  if (t >= 40960) return;
  int l = t & 63;
  int nt = (t >> 6) & 63;
  int kc = t >> 12;  // 0..9
  int row = nt * 16 + (l & 15);
  int cb = (l >> 4) * 8;
  unsigned short* dst = ws_w + (size_t)t * 8;
  const float* src = (kc < 2) ? (Wih + row * 64 + kc * 32 + cb)
                              : (Whh + row * 256 + (kc - 2) * 32 + cb);
#pragma unroll
  for (int j = 0; j < 8; j++) dst[j] = f2bf(src[j]);
}

// ---- Prologue 2: bias + scal ------------------------------------------------
extern "C" __global__ void prologue2(const float* __restrict__ b_ih,
                                     const float* __restrict__ b_hh,
                                     const float* __restrict__ ln2g,
                                     const float* __restrict__ ln2b,
                                     const float* __restrict__ posW,
                                     float* __restrict__ biasv,
                                     float* __restrict__ scal) {
  int t = threadIdx.x;  // 256
#pragma unroll
  for (int k2 = 0; k2 < 4; k2++) {
    int n = t * 4 + k2;
    biasv[n] = b_ih[n] + b_hh[n];
  }
  __shared__ float red[256][4];
  float g = ln2g[t], b = ln2b[t], p0 = posW[t], p1 = posW[256 + t];
  red[t][0] = b * p0;
  red[t][1] = b * p1;
  red[t][2] = g * p0;
  red[t][3] = g * p1;
  __syncthreads();
  for (int s = 128; s > 0; s >>= 1) {
    if (t < s) {
#pragma unroll
      for (int v = 0; v < 4; v++) red[t][v] += red[t + s][v];
    }
    __syncthreads();
  }
  if (t == 0) {
#pragma unroll
    for (int v = 0; v < 4; v++) scal[v] = red[0][v];
  }
}

// load one kc-block of B-frags (8 short8 = 32 VGPRs) into named set
#define LOAD_B(dst, kcv)                                                   \
  {                                                                        \
    const unsigned short* wp_ = wsw + (kcv)*32768;                         \
    _Pragma("unroll") for (int g_ = 0; g_ < 4; g_++)                       \
        _Pragma("unroll") for (int j_ = 0; j_ < 2; j_++)                   \
            dst[g_][j_] = *(const short8*)(wp_ + g_ * 8192 + j_ * 512);    \
  }

// 16 MFMAs of one kc stage: A-frags a0_ (mt0) / a1_ (mt1) x named B set
#define MFMA_STAGE(bset, a0e, a1e)                                         \
  {                                                                        \
    short8 a0_ = (a0e), a1_ = (a1e);                                       \
    _Pragma("unroll") for (int g_ = 0; g_ < 4; g_++)                       \
        _Pragma("unroll") for (int j_ = 0; j_ < 2; j_++) {                 \
      acc[0][g_][j_] = mfma16(a0_, bset[g_][j_], acc[0][g_][j_]);          \
      acc[1][g_][j_] = mfma16(a1_, bset[g_][j_], acc[1][g_][j_]);          \
    }                                                                      \
  }

#define XH(kc2, mt) (*(const short8*)(xh + ((mt)*2 + (kc2)) * 512 + loff))
#define HS(k, mt)   (*(const short8*)(h_stage + ((mt)*8 + (k)) * 512 + loff))

// ---- Main persistent decoder ------------------------------------------------
extern "C" __global__ __launch_bounds__(512, 1) void decoder_main(
    const float* __restrict__ lpr, const float* __restrict__ h0,
    const float* __restrict__ c0, const float* __restrict__ embW,
    const float* __restrict__ embB, const float* __restrict__ ln1g,
    const float* __restrict__ ln1b, const float* __restrict__ posW,
    const float* __restrict__ posB, const float* __restrict__ ln2g,
    const unsigned short* __restrict__ ws_w,
    const float* __restrict__ biasv, const float* __restrict__ scal,
    float* __restrict__ out) {
  __shared__ unsigned short h_stage[16 * 512];  // 16 KB: [mt*8+kc][l*8+j]
  __shared__ unsigned short xh[4 * 512];        // 4 KB:  [mt*2+kc][l*8+j]
  __shared__ float partials[32 * 8 * 4];        // 4 KB:  [ped][w] f32x4
  __shared__ float n01[32][2];

  const int bid = blockIdx.x;
  const int tid = threadIdx.x;
  const int w = tid >> 6, l = tid & 63;
  const int q = l >> 4, li = l & 15;
  const int P0 = bid * 32;
  const int loff = l * 8;
  const int u0 = w * 32 + li;  // + j*16

  // per-thread base into B-frag stream: + kc*32768 + g*8192 + j*512 (shorts)
  const unsigned short* wsw = ws_w + w * 1024 + loff;

  const float K0 = scal[0], K1 = scal[1], SP0 = scal[2], SP1 = scal[3];
  const float pb0 = posB[0], pb1 = posB[1];
  const float g10 = ln1g[0], g11 = ln1g[1], b10 = ln1b[0], b11 = ln1b[1];

  float bias_r[4][2];
#pragma unroll
  for (int g = 0; g < 4; g++)
#pragma unroll
    for (int j = 0; j < 2; j++) bias_r[g][j] = biasv[g * 256 + u0 + j * 16];
  float Pp0[2], Pp1[2];
#pragma unroll
  for (int j = 0; j < 2; j++) {
    float gg = ln2g[u0 + j * 16];
    Pp0[j] = gg * posW[u0 + j * 16];
    Pp1[j] = gg * posW[256 + u0 + j * 16];
  }

  // ---- c0 ----
  f32x4 c_r[2][2];
#pragma unroll
  for (int mt = 0; mt < 2; mt++)
#pragma unroll
    for (int j = 0; j < 2; j++)
#pragma unroll
      for (int r = 0; r < 4; r++)
        c_r[mt][j][r] =
            c0[(size_t)(P0 + mt * 16 + q * 4 + r) * 256 + u0 + j * 16];

  // ---- h0 -> h_stage A-frags (32 peds x 256 units) ----
#pragma unroll
  for (int it = 0; it < 2; it++) {
    int f = tid + it * 512;  // 0..1023 short8-slots
    int ll = f & 63, fr = f >> 6;  // frag 0..15
    int mt = fr >> 3, kc = fr & 7;
    const float* src = h0 + (size_t)(P0 + mt * 16 + (ll & 15)) * 256 +
                       kc * 32 + (ll >> 4) * 8;
    float4 ta = *(const float4*)(src);
    float4 tb = *(const float4*)(src + 4);
    short8 sv;
    sv[0] = (short)f2bf(ta.x); sv[1] = (short)f2bf(ta.y);
    sv[2] = (short)f2bf(ta.z); sv[3] = (short)f2bf(ta.w);
    sv[4] = (short)f2bf(tb.x); sv[5] = (short)f2bf(tb.y);
    sv[6] = (short)f2bf(tb.z); sv[7] = (short)f2bf(tb.w);
    *(short8*)(h_stage + f * 8) = sv;
  }

  // ---- n01 from lpr ----
  if (tid < 32) {
    float r0 = lpr[(P0 + tid) * 2], r1 = lpr[(P0 + tid) * 2 + 1];
    float d = 0.5f * (r0 - r1);
    float rs = rsqrtf(d * d + 1e-5f);
    n01[tid][0] = d * rs * g10 + b10;
    n01[tid][1] = -d * rs * g11 + b11;
  }
  __syncthreads();

  // ---- x0 = embed(n01) -> xh (16 threads/ped, 4 k each) ----
  {
    const int pc = tid >> 4, s16 = tid & 15;
    float n0 = n01[pc][0], n1 = n01[pc][1];
    int mt = pc >> 4, row = pc & 15;
#pragma unroll
    for (int jj = 0; jj < 4; jj++) {
      int k = s16 * 4 + jj;
      float e = n0 * embW[k * 2] + n1 * embW[k * 2 + 1] + embB[k];
      e = e > 0.f ? e : 0.01f * e;
      xh[(mt * 2 + (k >> 5)) * 512 + (row + 16 * ((k & 31) >> 3)) * 8 +
         (k & 7)] = f2bf(e);
    }
  }
  __syncthreads();

  // ---- named double-buffer B sets; prefetch kc0 ----
  short8 bA[4][2], bB[4][2];
  LOAD_B(bA, 0);

  for (int st = 0; st < 30; st++) {
    f32x4 acc[2][4][2];
#pragma unroll
    for (int mt = 0; mt < 2; mt++)
#pragma unroll
      for (int g = 0; g < 4; g++)
#pragma unroll
        for (int j = 0; j < 2; j++)
          acc[mt][g][j] = (f32x4){bias_r[g][j], bias_r[g][j], bias_r[g][j],
                                  bias_r[g][j]};

    // ---- 10 hand-unrolled kc stages; load s+1 into other set, MFMA s ----
    LOAD_B(bB, 1); MFMA_STAGE(bA, XH(0, 0), XH(0, 1));  // kc0
    LOAD_B(bA, 2); MFMA_STAGE(bB, XH(1, 0), XH(1, 1));  // kc1
    LOAD_B(bB, 3); MFMA_STAGE(bA, HS(0, 0), HS(0, 1));  // kc2
    LOAD_B(bA, 4); MFMA_STAGE(bB, HS(1, 0), HS(1, 1));  // kc3
    LOAD_B(bB, 5); MFMA_STAGE(bA, HS(2, 0), HS(2, 1));  // kc4
    LOAD_B(bA, 6); MFMA_STAGE(bB, HS(3, 0), HS(3, 1));  // kc5
    LOAD_B(bB, 7); MFMA_STAGE(bA, HS(4, 0), HS(4, 1));  // kc6
    LOAD_B(bA, 8); MFMA_STAGE(bB, HS(5, 0), HS(5, 1));  // kc7
    LOAD_B(bB, 9); MFMA_STAGE(bA, HS(6, 0), HS(6, 1));  // kc8
    LOAD_B(bA, 0); MFMA_STAGE(bB, HS(7, 0), HS(7, 1));  // kc9 (+next kc0)
    __syncthreads();  // A: all xh/h_stage reads done

    // ---- cell: c/h update, h -> h_stage A-frags, stats reduce ----
#pragma unroll
    for (int mt = 0; mt < 2; mt++) {
      float sh[4], sh2[4], sA[4], sB[4];
#pragma unroll
      for (int r = 0; r < 4; r++) {
        sh[r] = 0.f; sh2[r] = 0.f; sA[r] = 0.f; sB[r] = 0.f;
      }
#pragma unroll
      for (int j = 0; j < 2; j++) {
#pragma unroll
        for (int r = 0; r < 4; r++) {
          float iv = sigm(acc[mt][0][j][r]);
          float fv = sigm(acc[mt][1][j][r]);
          float gv = tanh_(acc[mt][2][j][r]);
          float ov = sigm(acc[mt][3][j][r]);
          float cc = fv * c_r[mt][j][r] + iv * gv;
          c_r[mt][j][r] = cc;
          float hv = ov * tanh_(cc);
          // unit u = w*32 + j*16 + li -> frag kc = w, col = j*16+li
          h_stage[(mt * 8 + w) * 512 +
                  ((q * 4 + r) + 16 * (j * 2 + (li >> 3))) * 8 + (li & 7)] =
              f2bf(hv);
          sh[r] += hv;
          sh2[r] += hv * hv;
          sA[r] += hv * Pp0[j];
          sB[r] += hv * Pp1[j];
        }
      }
#pragma unroll
      for (int mask = 1; mask <= 8; mask <<= 1) {
#pragma unroll
        for (int r = 0; r < 4; r++) {
          sh[r] += __shfl_xor(sh[r], mask, 64);
          sh2[r] += __shfl_xor(sh2[r], mask, 64);
          sA[r] += __shfl_xor(sA[r], mask, 64);
          sB[r] += __shfl_xor(sB[r], mask, 64);
        }
      }
      if (li == 0) {
#pragma unroll
        for (int r = 0; r < 4; r++)
          *(f32x4*)(partials + ((mt * 16 + q * 4 + r) * 8 + w) * 4) =
              (f32x4){sh[r], sh2[r], sA[r], sB[r]};
      }
    }
    __syncthreads();  // B: h_stage(t+1) + partials complete

    // ---- LN + rel + out + n01 (one thread per ped) ----
    if (tid < 32) {
      f32x4 sv = *(const f32x4*)(partials + tid * 32);
#pragma unroll
      for (int ww = 1; ww < 8; ww++) {
        f32x4 t2 = *(const f32x4*)(partials + (tid * 8 + ww) * 4);
        sv.x += t2.x; sv.y += t2.y; sv.z += t2.z; sv.w += t2.w;
      }
      float mu = sv.x * (1.0f / 256.0f);
      float var = sv.y * (1.0f / 256.0f) - mu * mu;
      float rsig = rsqrtf(var + 1e-5f);
      float rel0 = sigm(rsig * (sv.z - mu * SP0) + K0 + pb0);
      float rel1 = sigm(rsig * (sv.w - mu * SP1) + K1 + pb1);
      *(float2*)(out + (size_t)st * 16384 + (P0 + tid) * 2) =
          make_float2(rel0, rel1);
      float d = 0.5f * (rel0 - rel1);
      float rs = rsqrtf(d * d + 1e-5f);
      n01[tid][0] = d * rs * g10 + b10;
      n01[tid][1] = -d * rs * g11 + b11;
    }
    __syncthreads();  // C: n01 ready

    // ---- x_{t+1} = embed(rel) -> xh ----
    {
      const int pc = tid >> 4, s16 = tid & 15;
      float n0 = n01[pc][0], n1 = n01[pc][1];
      int mt = pc >> 4, row = pc & 15;
#pragma unroll
      for (int jj = 0; jj < 4; jj++) {
        int k = s16 * 4 + jj;
        float e = n0 * embW[k * 2] + n1 * embW[k * 2 + 1] + embB[k];
        e = e > 0.f ? e : 0.01f * e;
        xh[(mt * 2 + (k >> 5)) * 512 + (row + 16 * ((k & 31) >> 3)) * 8 +
           (k & 7)] = f2bf(e);
      }
    }
    __syncthreads();  // D: xh ready for next step
  }
}

extern "C" void kernel_launch(void* const* d_in, const int* in_sizes, int n_in,
                              void* d_out, int out_size, void* d_ws,
                              size_t ws_size, hipStream_t stream) {
  (void)in_sizes; (void)n_in; (void)out_size; (void)ws_size;
  const float* lpr  = (const float*)d_in[1];
  const float* h0   = (const float*)d_in[2];
  const float* c0   = (const float*)d_in[3];
  const float* Wih  = (const float*)d_in[4];
  const float* Whh  = (const float*)d_in[5];
  const float* b_ih = (const float*)d_in[6];
  const float* b_hh = (const float*)d_in[7];
  const float* embW = (const float*)d_in[8];
  const float* embB = (const float*)d_in[9];
  const float* ln1g = (const float*)d_in[10];
  const float* ln1b = (const float*)d_in[11];
  const float* posW = (const float*)d_in[12];
  const float* posB = (const float*)d_in[13];
  const float* ln2g = (const float*)d_in[14];
  const float* ln2b = (const float*)d_in[15];

  char* ws = (char*)d_ws;
  unsigned short* ws_w = (unsigned short*)(ws + WS_W);
  float* biasv  = (float*)(ws + WS_BIAS);
  float* scal   = (float*)(ws + WS_SCAL);

  shuffle_weights<<<dim3(160), dim3(256), 0, stream>>>(Wih, Whh, ws_w);
  prologue2<<<dim3(1), dim3(256), 0, stream>>>(b_ih, b_hh, ln2g, ln2b, posW,
                                               biasv, scal);
  decoder_main<<<dim3(256), dim3(512), 0, stream>>>(
      lpr, h0, c0, embW, embB, ln1g, ln1b, posW, posB, ln2g, ws_w, biasv,
      scal, (float*)d_out);
}

// Round 4
// 775.389 us; speedup vs baseline: 1.1708x; 1.1693x over previous
//
#include <hip/hip_runtime.h>

// DecoderLSTM R13: weight stream moved to async global->LDS DMA.
// Evidence R10-R12: byte-identical counters across 3 "different" kernels
// (full unroll made them the same IR). 127 MB of unexplained global writes
// (33 B/thread/step) = compiler spill stream; FETCH 1.89 GB at 2.26 TB/s =
// latency*concurrency-limited weight refetch. Fix both by removing B-frags
// from registers: 2x64KB LDS double-buffer filled by global_load_lds(16B),
// each wave DMAs exactly the 8x1KB chunks it alone reads (no cross-wave
// dependency -> per-wave vmcnt(8) only, no extra barriers). Slab k+2 issued
// at stage k -> ~2 MFMA-stages of latency cover. Arch-VGPR demand ~90.
// Rest identical to R12: 256 blocks x 512 thr, 32 peds x 256 units/block,
// MFMA 16x16x32 bf16, 4 __syncthreads/step, no cross-block traffic.

typedef float  f32x4  __attribute__((ext_vector_type(4)));
typedef short  short8 __attribute__((ext_vector_type(8)));
typedef __bf16 bf16x8 __attribute__((ext_vector_type(8)));

#define WS_W     0                      // 640 KB bf16 B-frags
#define WS_BIAS  (640 * 1024)           // 4 KB
#define WS_SCAL  (WS_BIAS + 4096)       // 64 B

__device__ __forceinline__ unsigned short f2bf(float f) {
  unsigned int u = __float_as_uint(f);
  u += 0x7FFFu + ((u >> 16) & 1u);  // RNE
  return (unsigned short)(u >> 16);
}
__device__ __forceinline__ float sigm(float x) {
  return __builtin_amdgcn_rcpf(1.0f + __expf(-x));
}
__device__ __forceinline__ float tanh_(float x) {
  float ax = fabsf(x);
  float t = __expf(-2.0f * ax);
  float r = (1.0f - t) * __builtin_amdgcn_rcpf(1.0f + t);
  return x >= 0.0f ? r : -r;
}
__device__ __forceinline__ f32x4 mfma16(short8 a, short8 b, f32x4 c) {
  return __builtin_amdgcn_mfma_f32_16x16x32_bf16(
      __builtin_bit_cast(bf16x8, a), __builtin_bit_cast(bf16x8, b), c, 0, 0, 0);
}

// ---- Prologue 1: weights -> B-frag bf16 ------------------------------------
// flat short idx = (kc*64 + nt)*512 + l*8 + j   (kc-major: slab = 64KB)
extern "C" __global__ void shuffle_weights(const float* __restrict__ Wih,
                                           const float* __restrict__ Whh,
                                           unsigned short* __restrict__ ws_w) {
  int t = blockIdx.x * 256 + threadIdx.x;  // 0..40959
  if (t >= 40960) return;
  int l = t & 63;
  int nt = (t >> 6) & 63;
  int kc = t >> 12;  // 0..9
  int row = nt * 16 + (l & 15);
  int cb = (l >> 4) * 8;
  unsigned short* dst = ws_w + (size_t)t * 8;
  const float* src = (kc < 2) ? (Wih + row * 64 + kc * 32 + cb)
                              : (Whh + row * 256 + (kc - 2) * 32 + cb);
#pragma unroll
  for (int j = 0; j < 8; j++) dst[j] = f2bf(src[j]);
}

// ---- Prologue 2: bias + scal ------------------------------------------------
extern "C" __global__ void prologue2(const float* __restrict__ b_ih,
                                     const float* __restrict__ b_hh,
                                     const float* __restrict__ ln2g,
                                     const float* __restrict__ ln2b,
                                     const float* __restrict__ posW,
                                     float* __restrict__ biasv,
                                     float* __restrict__ scal) {
  int t = threadIdx.x;  // 256
#pragma unroll
  for (int k2 = 0; k2 < 4; k2++) {
    int n = t * 4 + k2;
    biasv[n] = b_ih[n] + b_hh[n];
  }
  __shared__ float red[256][4];
  float g = ln2g[t], b = ln2b[t], p0 = posW[t], p1 = posW[256 + t];
  red[t][0] = b * p0;
  red[t][1] = b * p1;
  red[t][2] = g * p0;
  red[t][3] = g * p1;
  __syncthreads();
  for (int s = 128; s > 0; s >>= 1) {
    if (t < s) {
#pragma unroll
      for (int v = 0; v < 4; v++) red[t][v] += red[t + s][v];
    }
    __syncthreads();
  }
  if (t == 0) {
#pragma unroll
    for (int v = 0; v < 4; v++) scal[v] = red[0][v];
  }
}

// DMA one kc-slab's wave-slice: 8 calls x 1KB, wave w writes/reads only its
// own chunks (g*8192 + j*512 + w*1024 shorts). LDS dest wave-uniform;
// global src per-lane (+ loff). size literal 16.
#define DMA_SLAB(kcv, bufv)                                                  \
  {                                                                          \
    const unsigned short* gs_ = ws_w + (kcv)*32768 + w * 1024 + loff;        \
    unsigned short* ls_ = &wbuf[(bufv)][w * 1024];                           \
    _Pragma("unroll") for (int g_ = 0; g_ < 4; g_++)                         \
        _Pragma("unroll") for (int j_ = 0; j_ < 2; j_++)                     \
            __builtin_amdgcn_global_load_lds(                                \
                (const unsigned int*)(gs_ + g_ * 8192 + j_ * 512),           \
                (unsigned int*)(ls_ + g_ * 8192 + j_ * 512), 16, 0, 0);      \
  }

// One kc stage: wait slab resident (vmcnt(8): slab kc+1 stays in flight),
// ds_read 8 B-frags + 16 MFMA, then overwrite this buffer with slab kc+2.
#define STAGE(kcv, a0e, a1e)                                                 \
  {                                                                          \
    asm volatile("s_waitcnt vmcnt(8)" ::: "memory");                         \
    short8 a0_ = (a0e), a1_ = (a1e);                                         \
    const unsigned short* lb_ = &wbuf[(kcv)&1][w * 1024 + loff];             \
    _Pragma("unroll") for (int g_ = 0; g_ < 4; g_++) {                       \
      short8 b0_ = *(const short8*)(lb_ + g_ * 8192);                        \
      short8 b1_ = *(const short8*)(lb_ + g_ * 8192 + 512);                  \
      acc[0][g_][0] = mfma16(a0_, b0_, acc[0][g_][0]);                       \
      acc[1][g_][0] = mfma16(a1_, b0_, acc[1][g_][0]);                       \
      acc[0][g_][1] = mfma16(a0_, b1_, acc[0][g_][1]);                       \
      acc[1][g_][1] = mfma16(a1_, b1_, acc[1][g_][1]);                       \
    }                                                                        \
    asm volatile("s_waitcnt lgkmcnt(0)" ::: "memory");                       \
    DMA_SLAB(((kcv) + 2) % 10, (kcv)&1);                                     \
  }

#define XH(kc2, mt) (*(const short8*)(xh + ((mt)*2 + (kc2)) * 512 + loff))
#define HS(k, mt)   (*(const short8*)(h_stage + ((mt)*8 + (k)) * 512 + loff))

// ---- Main persistent decoder ------------------------------------------------
extern "C" __global__ __launch_bounds__(512, 1) void decoder_main(
    const float* __restrict__ lpr, const float* __restrict__ h0,
    const float* __restrict__ c0, const float* __restrict__ embW,
    const float* __restrict__ embB, const float* __restrict__ ln1g,
    const float* __restrict__ ln1b, const float* __restrict__ posW,
    const float* __restrict__ posB, const float* __restrict__ ln2g,
    const unsigned short* __restrict__ ws_w,
    const float* __restrict__ biasv, const float* __restrict__ scal,
    float* __restrict__ out) {
  __shared__ unsigned short wbuf[2][32768];     // 128 KB weight slab dbuf
  __shared__ unsigned short h_stage[16 * 512];  // 16 KB: [mt*8+kc][l*8+j]
  __shared__ unsigned short xh[4 * 512];        // 4 KB:  [mt*2+kc][l*8+j]
  __shared__ float partials[32 * 8 * 4];        // 4 KB:  [ped][w] f32x4
  __shared__ float n01[32][2];

  const int bid = blockIdx.x;
  const int tid = threadIdx.x;
  const int w = tid >> 6, l = tid & 63;
  const int q = l >> 4, li = l & 15;
  const int P0 = bid * 32;
  const int loff = l * 8;
  const int u0 = w * 32 + li;  // + j*16

  const float K0 = scal[0], K1 = scal[1], SP0 = scal[2], SP1 = scal[3];
  const float pb0 = posB[0], pb1 = posB[1];
  const float g10 = ln1g[0], g11 = ln1g[1], b10 = ln1b[0], b11 = ln1b[1];

  float bias_r[4][2];
#pragma unroll
  for (int g = 0; g < 4; g++)
#pragma unroll
    for (int j = 0; j < 2; j++) bias_r[g][j] = biasv[g * 256 + u0 + j * 16];
  float Pp0[2], Pp1[2];
#pragma unroll
  for (int j = 0; j < 2; j++) {
    float gg = ln2g[u0 + j * 16];
    Pp0[j] = gg * posW[u0 + j * 16];
    Pp1[j] = gg * posW[256 + u0 + j * 16];
  }

  // ---- c0 ----
  f32x4 c_r[2][2];
#pragma unroll
  for (int mt = 0; mt < 2; mt++)
#pragma unroll
    for (int j = 0; j < 2; j++)
#pragma unroll
      for (int r = 0; r < 4; r++)
        c_r[mt][j][r] =
            c0[(size_t)(P0 + mt * 16 + q * 4 + r) * 256 + u0 + j * 16];

  // ---- h0 -> h_stage A-frags (32 peds x 256 units) ----
#pragma unroll
  for (int it = 0; it < 2; it++) {
    int f = tid + it * 512;  // 0..1023 short8-slots
    int ll = f & 63, fr = f >> 6;  // frag 0..15
    int mt = fr >> 3, kc = fr & 7;
    const float* src = h0 + (size_t)(P0 + mt * 16 + (ll & 15)) * 256 +
                       kc * 32 + (ll >> 4) * 8;
    float4 ta = *(const float4*)(src);
    float4 tb = *(const float4*)(src + 4);
    short8 sv;
    sv[0] = (short)f2bf(ta.x); sv[1] = (short)f2bf(ta.y);
    sv[2] = (short)f2bf(ta.z); sv[3] = (short)f2bf(ta.w);
    sv[4] = (short)f2bf(tb.x); sv[5] = (short)f2bf(tb.y);
    sv[6] = (short)f2bf(tb.z); sv[7] = (short)f2bf(tb.w);
    *(short8*)(h_stage + f * 8) = sv;
  }

  // ---- n01 from lpr ----
  if (tid < 32) {
    float r0 = lpr[(P0 + tid) * 2], r1 = lpr[(P0 + tid) * 2 + 1];
    float d = 0.5f * (r0 - r1);
    float rs = rsqrtf(d * d + 1e-5f);
    n01[tid][0] = d * rs * g10 + b10;
    n01[tid][1] = -d * rs * g11 + b11;
  }
  __syncthreads();

  // ---- x0 = embed(n01) -> xh (16 threads/ped, 4 k each) ----
  {
    const int pc = tid >> 4, s16 = tid & 15;
    float n0 = n01[pc][0], n1 = n01[pc][1];
    int mt = pc >> 4, row = pc & 15;
#pragma unroll
    for (int jj = 0; jj < 4; jj++) {
      int k = s16 * 4 + jj;
      float e = n0 * embW[k * 2] + n1 * embW[k * 2 + 1] + embB[k];
      e = e > 0.f ? e : 0.01f * e;
      xh[(mt * 2 + (k >> 5)) * 512 + (row + 16 * ((k & 31) >> 3)) * 8 +
         (k & 7)] = f2bf(e);
    }
  }
  __syncthreads();

  // ---- prime the DMA pipeline: slab0 -> buf0, slab1 -> buf1 ----
  DMA_SLAB(0, 0);
  DMA_SLAB(1, 1);

  for (int st = 0; st < 30; st++) {
    f32x4 acc[2][4][2];
#pragma unroll
    for (int mt = 0; mt < 2; mt++)
#pragma unroll
      for (int g = 0; g < 4; g++)
#pragma unroll
        for (int j = 0; j < 2; j++)
          acc[mt][g][j] = (f32x4){bias_r[g][j], bias_r[g][j], bias_r[g][j],
                                  bias_r[g][j]};

    // ---- 10 kc stages, weights via LDS dbuf + async DMA ----
    STAGE(0, XH(0, 0), XH(0, 1));
    STAGE(1, XH(1, 0), XH(1, 1));
    STAGE(2, HS(0, 0), HS(0, 1));
    STAGE(3, HS(1, 0), HS(1, 1));
    STAGE(4, HS(2, 0), HS(2, 1));
    STAGE(5, HS(3, 0), HS(3, 1));
    STAGE(6, HS(4, 0), HS(4, 1));
    STAGE(7, HS(5, 0), HS(5, 1));
    STAGE(8, HS(6, 0), HS(6, 1));  // DMAs next step's slab0
    STAGE(9, HS(7, 0), HS(7, 1));  // DMAs next step's slab1
    __syncthreads();  // A: all xh/h_stage reads done

    // ---- cell: c/h update, h -> h_stage A-frags, stats reduce ----
#pragma unroll
    for (int mt = 0; mt < 2; mt++) {
      float sh[4], sh2[4], sA[4], sB[4];
#pragma unroll
      for (int r = 0; r < 4; r++) {
        sh[r] = 0.f; sh2[r] = 0.f; sA[r] = 0.f; sB[r] = 0.f;
      }
#pragma unroll
      for (int j = 0; j < 2; j++) {
#pragma unroll
        for (int r = 0; r < 4; r++) {
          float iv = sigm(acc[mt][0][j][r]);
          float fv = sigm(acc[mt][1][j][r]);
          float gv = tanh_(acc[mt][2][j][r]);
          float ov = sigm(acc[mt][3][j][r]);
          float cc = fv * c_r[mt][j][r] + iv * gv;
          c_r[mt][j][r] = cc;
          float hv = ov * tanh_(cc);
          // unit u = w*32 + j*16 + li -> frag kc = w, col = j*16+li
          h_stage[(mt * 8 + w) * 512 +
                  ((q * 4 + r) + 16 * (j * 2 + (li >> 3))) * 8 + (li & 7)] =
              f2bf(hv);
          sh[r] += hv;
          sh2[r] += hv * hv;
          sA[r] += hv * Pp0[j];
          sB[r] += hv * Pp1[j];
        }
      }
#pragma unroll
      for (int mask = 1; mask <= 8; mask <<= 1) {
#pragma unroll
        for (int r = 0; r < 4; r++) {
          sh[r] += __shfl_xor(sh[r], mask, 64);
          sh2[r] += __shfl_xor(sh2[r], mask, 64);
          sA[r] += __shfl_xor(sA[r], mask, 64);
          sB[r] += __shfl_xor(sB[r], mask, 64);
        }
      }
      if (li == 0) {
#pragma unroll
        for (int r = 0; r < 4; r++)
          *(f32x4*)(partials + ((mt * 16 + q * 4 + r) * 8 + w) * 4) =
              (f32x4){sh[r], sh2[r], sA[r], sB[r]};
      }
    }
    __syncthreads();  // B: h_stage(t+1) + partials complete

    // ---- LN + rel + out + n01 (one thread per ped) ----
    if (tid < 32) {
      f32x4 sv = *(const f32x4*)(partials + tid * 32);
#pragma unroll
      for (int ww = 1; ww < 8; ww++) {
        f32x4 t2 = *(const f32x4*)(partials + (tid * 8 + ww) * 4);
        sv.x += t2.x; sv.y += t2.y; sv.z += t2.z; sv.w += t2.w;
      }
      float mu = sv.x * (1.0f / 256.0f);
      float var = sv.y * (1.0f / 256.0f) - mu * mu;
      float rsig = rsqrtf(var + 1e-5f);
      float rel0 = sigm(rsig * (sv.z - mu * SP0) + K0 + pb0);
      float rel1 = sigm(rsig * (sv.w - mu * SP1) + K1 + pb1);
      *(float2*)(out + (size_t)st * 16384 + (P0 + tid) * 2) =
          make_float2(rel0, rel1);
      float d = 0.5f * (rel0 - rel1);
      float rs = rsqrtf(d * d + 1e-5f);
      n01[tid][0] = d * rs * g10 + b10;
      n01[tid][1] = -d * rs * g11 + b11;
    }
    __syncthreads();  // C: n01 ready

    // ---- x_{t+1} = embed(rel) -> xh ----
    {
      const int pc = tid >> 4, s16 = tid & 15;
      float n0 = n01[pc][0], n1 = n01[pc][1];
      int mt = pc >> 4, row = pc & 15;
#pragma unroll
      for (int jj = 0; jj < 4; jj++) {
        int k = s16 * 4 + jj;
        float e = n0 * embW[k * 2] + n1 * embW[k * 2 + 1] + embB[k];
        e = e > 0.f ? e : 0.01f * e;
        xh[(mt * 2 + (k >> 5)) * 512 + (row + 16 * ((k & 31) >> 3)) * 8 +
           (k & 7)] = f2bf(e);
      }
    }
    __syncthreads();  // D: xh ready for next step
  }
}

extern "C" void kernel_launch(void* const* d_in, const int* in_sizes, int n_in,
                              void* d_out, int out_size, void* d_ws,
                              size_t ws_size, hipStream_t stream) {
  (void)in_sizes; (void)n_in; (void)out_size; (void)ws_size;
  const float* lpr  = (const float*)d_in[1];
  const float* h0   = (const float*)d_in[2];
  const float* c0   = (const float*)d_in[3];
  const float* Wih  = (const float*)d_in[4];
  const float* Whh  = (const float*)d_in[5];
  const float* b_ih = (const float*)d_in[6];
  const float* b_hh = (const float*)d_in[7];
  const float* embW = (const float*)d_in[8];
  const float* embB = (const float*)d_in[9];
  const float* ln1g = (const float*)d_in[10];
  const float* ln1b = (const float*)d_in[11];
  const float* posW = (const float*)d_in[12];
  const float* posB = (const float*)d_in[13];
  const float* ln2g = (const float*)d_in[14];
  const float* ln2b = (const float*)d_in[15];

  char* ws = (char*)d_ws;
  unsigned short* ws_w = (unsigned short*)(ws + WS_W);
  float* biasv  = (float*)(ws + WS_BIAS);
  float* scal   = (float*)(ws + WS_SCAL);

  shuffle_weights<<<dim3(160), dim3(256), 0, stream>>>(Wih, Whh, ws_w);
  prologue2<<<dim3(1), dim3(256), 0, stream>>>(b_ih, b_hh, ln2g, ln2b, posW,
                                               biasv, scal);
  decoder_main<<<dim3(256), dim3(512), 0, stream>>>(
      lpr, h0, c0, embW, embB, ln1g, ln1b, posW, posB, ln2g, ws_w, biasv,
      scal, (float*)d_out);
}